// Round 6
// baseline (456.201 us; speedup 1.0000x reference)
//
#include <hip/hip_runtime.h>
#include <hip/hip_bf16.h>

// HopfieldLayer: out = softmax(x @ Wl^T * beta) @ Wc^T
//   x [16384,768] f32, Wl [4096,768] f32, Wc [768,4096] f32 -> out [16384,768] f32
// R9: m201-faithful staging/layout on R8's 8-phase ledger. LDS = row-major
// [128][64] bf16 half-tiles; stage via global_load_lds with LINEAR dest
// (uniform base + lane*16) and PRE-SWIZZLED global source (8x128B runs per
// inst -- line-contiguous, vs R8's 16x64B scattered fragment-ordered source);
// reads via ds_read_b128 with the same involution swizzle:
//   byte ^= ((row&7)<<4)   (within-row permutation; af/bg reads 2 lanes/bank)
// Schedule identical to R8: bare s_barrier, lgkm0 (no sched_barrier, m141),
// vmcnt(6) at P4/P8 only, setprio around MFMA.

#define NTOK   16384
#define DIM    768
#define NPROT  4096
#define BETA_F 0.03608439182428583f

typedef __bf16 bf16_t;
typedef __bf16 bf16x8 __attribute__((ext_vector_type(8)));
typedef float  floatx4 __attribute__((ext_vector_type(4)));

// ---------------------------------------------------------------- async 16B copy
__device__ __forceinline__ void async_copy16(const bf16_t* g, void* l) {
  __builtin_amdgcn_global_load_lds(
      (__attribute__((address_space(1))) const void*)g,
      (__attribute__((address_space(3))) void*)l, 16, 0, 0);
}

// ---------------------------------------------------------------- f32 -> bf16
__global__ __launch_bounds__(256) void cvt_all(
    const float* __restrict__ x, const float* __restrict__ wl,
    const float* __restrict__ wc, bf16_t* __restrict__ xb,
    bf16_t* __restrict__ wlb, bf16_t* __restrict__ wcb,
    int nx8, int nw8, int nc8) {
  int i = blockIdx.x * 256 + threadIdx.x;
  const float* in; bf16_t* out; int k;
  if (i < nx8)            { in = x;  out = xb;  k = i; }
  else if (i < nx8 + nw8) { in = wl; out = wlb; k = i - nx8; }
  else if (i < nx8 + nw8 + nc8) { in = wc; out = wcb; k = i - nx8 - nw8; }
  else return;
  const float4* in4 = (const float4*)in;
  float4 a = in4[2 * k], b = in4[2 * k + 1];
  bf16x8 o;
  o[0] = (bf16_t)a.x; o[1] = (bf16_t)a.y; o[2] = (bf16_t)a.z; o[3] = (bf16_t)a.w;
  o[4] = (bf16_t)b.x; o[5] = (bf16_t)b.y; o[6] = (bf16_t)b.z; o[7] = (bf16_t)b.w;
  ((bf16x8*)out)[k] = o;
}

// ---------------------------------------------------------------- gemm C = A * B^T
// 256x256 tile, BK=64, 8 waves 2(M)x4(N). LDS per slot (64KB):
//   A-h0 [128][64]bf16 @0, A-h1 @16384, B-h0 @32768, B-h1 @49152 (row-major,
//   swizzled: LDS[row*128 + (kb ^ ((row&7)<<4))] = logical[row][kb]).
// Stage: thread tid, chunk j -> dest (j*512+tid)*16 within the 16KB half
//   (wave-uniform base (j*8+w)*1024 + lane*16); source row = j*64 + tid/8,
//   kbytes = ((tid&7)^(row&7))*16 -- the inverse (=same) swizzle.
// Reads: af/bg fragment (16 rows x 16B chunk c): addr = row*128 + (c^(lr&7))*16.
// 8 phases / 2 K-tiles, ledger identical to R8 (verified):
//   P1 stage A(t+1)h1, P2 A(t+2)h0, P3 B(t+2)h0, P4 B(t+2)h1 +VM(6),
//   P5 A(t+2)h1, P6 A(t+3)h0, P7 B(t+3)h0, P8 B(t+3)h1 +VM(6).
template <int EPI>
__global__ __launch_bounds__(512, 2)
void gemm256(const bf16_t* __restrict__ A, const bf16_t* __restrict__ B,
             void* __restrict__ Cv, float* __restrict__ rowsum,
             const int K, const int N, const int nN) {
  __shared__ char lds[131072];

  const int tid = threadIdx.x;
  const int l   = tid & 63;
  const int w   = tid >> 6;       // 0..7
  const int wr  = w >> 2;         // 0..1  (M)
  const int wc  = w & 3;          // 0..3  (N)
  const int lr  = l & 15;
  const int hb  = l >> 4;         // 0..3 (16B chunk sub-index for reads)
  const int cx  = lr & 7;         // read-side swizzle term (= row&7)

  // bijective XCD swizzle (nwg % 8 == 0); n-fast within chunk
  const int nwg   = gridDim.x;
  const int chunk = nwg >> 3;
  const int wg    = (blockIdx.x & 7) * chunk + (blockIdx.x >> 3);
  const int m0    = (wg / nN) * 256;
  const int n0    = (wg % nN) * 256;

  // staging source offsets (elements, kt=0): row = h*128 + j*64 + tid/8,
  // k-elems = ((tid&7) ^ ((tid>>3)&7)) * 8   (pre-swizzled source)
  const int r8   = tid >> 3;                      // 0..63
  const int eoff = (((tid & 7) ^ (r8 & 7)) << 3); // swizzled k element offset
  int aoff[2][2], boff[2][2];
#pragma unroll
  for (int h = 0; h < 2; ++h)
#pragma unroll
    for (int j = 0; j < 2; ++j) {
      aoff[h][j] = (m0 + h * 128 + j * 64 + r8) * K + eoff;
      boff[h][j] = (n0 + h * 128 + j * 64 + r8) * K + eoff;
    }

  auto stageA = [&](int slot, int kt, int h) {
#pragma unroll
    for (int j = 0; j < 2; ++j)
      async_copy16(A + aoff[h][j] + kt * 64,
                   lds + slot * 65536 + h * 16384 + ((j * 8 + w) << 10) + (l << 4));
  };
  auto stageB = [&](int slot, int kt, int h) {
#pragma unroll
    for (int j = 0; j < 2; ++j)
      async_copy16(B + boff[h][j] + kt * 64,
                   lds + slot * 65536 + 32768 + h * 16384 +
                       ((j * 8 + w) << 10) + (l << 4));
  };

  bf16x8 af[4][2], bg[4][2];
  // af[q][ks] <- A rows (q*2+wr)*16+lr of half mh, k-chunk c = ks*4+hb
  auto loadA = [&](int slot, int mh) {
#pragma unroll
    for (int q = 0; q < 4; ++q)
#pragma unroll
      for (int ks = 0; ks < 2; ++ks) {
        const int row = (q * 2 + wr) * 16 + lr;
        const int c   = ks * 4 + hb;
        af[q][ks] = *(const bf16x8*)(lds + slot * 65536 + mh * 16384 +
                        row * 128 + ((c ^ cx) << 4));
      }
  };
  // bg[qb+q][ks] <- B rows (q*4+wc)*16+lr of half nh
  auto loadB = [&](int slot, int nh, int qb) {
#pragma unroll
    for (int q = 0; q < 2; ++q)
#pragma unroll
      for (int ks = 0; ks < 2; ++ks) {
        const int row = (q * 4 + wc) * 16 + lr;
        const int c   = ks * 4 + hb;
        bg[qb + q][ks] = *(const bf16x8*)(lds + slot * 65536 + 32768 +
                        nh * 16384 + row * 128 + ((c ^ cx) << 4));
      }
  };

  const floatx4 z = {0.f, 0.f, 0.f, 0.f};
  floatx4 acc[8][4];
#pragma unroll
  for (int mt = 0; mt < 8; ++mt)
#pragma unroll
    for (int nt = 0; nt < 4; ++nt) acc[mt][nt] = z;

  auto mma = [&](int mq, int nq) {  // quadrant: mt = mq*4+q, nt = nq*2+r
    __builtin_amdgcn_s_setprio(1);
#pragma unroll
    for (int q = 0; q < 4; ++q)
#pragma unroll
      for (int r = 0; r < 2; ++r)
#pragma unroll
        for (int ks = 0; ks < 2; ++ks)
          acc[mq * 4 + q][nq * 2 + r] = __builtin_amdgcn_mfma_f32_16x16x32_bf16(
              af[q][ks], bg[nq * 2 + r][ks], acc[mq * 4 + q][nq * 2 + r], 0, 0, 0);
    __builtin_amdgcn_s_setprio(0);
  };

#define BAR()    __builtin_amdgcn_s_barrier()
#define LGKM0()  asm volatile("s_waitcnt lgkmcnt(0)")
#define LGKM8()  asm volatile("s_waitcnt lgkmcnt(8)")
#define VM(n)    asm volatile("s_waitcnt vmcnt(" #n ")" ::: "memory")

  const int T = K >> 6;  // K-tiles: 12 (K=768) or 64 (K=4096); both even, >=4

  // prologue: tile0 full (A0,B0,B1,A1) + tile1 {A0,B0,B1}; tile1.A1 at p1 of it 0
  stageA(0, 0, 0); stageB(0, 0, 0); stageB(0, 0, 1); stageA(0, 0, 1);
  stageA(1, 1, 0); stageB(1, 1, 0); stageB(1, 1, 1);
  VM(6);  // tile0 fully landed; tile1's 3 halves remain in flight
  BAR();

#pragma unroll 1
  for (int t = 0; t < T - 2; t += 2) {
    // P1: compute (t, mLo x nLo); stage (t+1).A-h1
    loadA(0, 0); loadB(0, 0, 0);
    stageA(1, t + 1, 1);
    LGKM8();
    BAR(); LGKM0(); mma(0, 0); BAR();
    // P2: (t, mLo x nHi); stage (t+2).A-h0 (slot0 A-h0 died in P1)
    loadB(0, 1, 2);
    stageA(0, t + 2, 0);
    BAR(); LGKM0(); mma(0, 1); BAR();
    // P3: (t, mHi x nHi); stage (t+2).B-h0
    loadA(0, 1);
    stageB(0, t + 2, 0);
    BAR(); LGKM0(); mma(1, 1); BAR();
    // P4: (t, mHi x nLo); stage (t+2).B-h1; vmcnt(6) -> tile t+1 fully landed
    stageB(0, t + 2, 1);
    BAR(); mma(1, 0); VM(6); BAR();
    // P5: compute (t+1, mLo x nLo); stage (t+2).A-h1
    loadA(1, 0); loadB(1, 0, 0);
    stageA(0, t + 2, 1);
    LGKM8();
    BAR(); LGKM0(); mma(0, 0); BAR();
    // P6: (t+1, mLo x nHi); stage (t+3).A-h0
    loadB(1, 1, 2);
    stageA(1, t + 3, 0);
    BAR(); LGKM0(); mma(0, 1); BAR();
    // P7: (t+1, mHi x nHi); stage (t+3).B-h0
    loadA(1, 1);
    stageB(1, t + 3, 0);
    BAR(); LGKM0(); mma(1, 1); BAR();
    // P8: (t+1, mHi x nLo); stage (t+3).B-h1; vmcnt(6) -> tile t+2 fully landed
    stageB(1, t + 3, 1);
    BAR(); mma(1, 0); VM(6); BAR();
  }

  // peeled last pair (t = T-2, T-1): only (T-1).A-h1 left to stage
  loadA(0, 0); loadB(0, 0, 0);
  stageA(1, T - 1, 1);
  LGKM8();
  BAR(); LGKM0(); mma(0, 0); BAR();
  loadB(0, 1, 2);
  BAR(); LGKM0(); mma(0, 1); BAR();
  loadA(0, 1);
  BAR(); LGKM0(); mma(1, 1); BAR();
  BAR(); mma(1, 0); VM(0); BAR();   // drain: (T-1).A-h1 landed
  loadA(1, 0); loadB(1, 0, 0);
  BAR(); LGKM0(); mma(0, 0); BAR();
  loadB(1, 1, 2);
  BAR(); LGKM0(); mma(0, 1); BAR();
  loadA(1, 1);
  BAR(); LGKM0(); mma(1, 1); BAR();
  mma(1, 0);

#undef BAR
#undef LGKM0
#undef LGKM8
#undef VM

  // C/D layout: col = lane&15, row = (lane>>4)*4 + i
  // frag (mt,nt): row = m0+(mt*2+wr)*16+(l>>4)*4+i, col = n0+(nt*4+wc)*16+lr
  const int hi4 = (l >> 4) << 2;
  if (EPI == 0) {
    bf16_t* P = (bf16_t*)Cv;
#pragma unroll
    for (int mt = 0; mt < 8; ++mt) {
      const int row = m0 + (mt * 2 + wr) * 16 + hi4;
      float rs[4] = {0.f, 0.f, 0.f, 0.f};
#pragma unroll
      for (int nt = 0; nt < 4; ++nt) {
        const int col = n0 + (nt * 4 + wc) * 16 + lr;
#pragma unroll
        for (int i = 0; i < 4; ++i) {
          const float e = __expf(acc[mt][nt][i] * BETA_F);
          P[(row + i) * N + col] = (bf16_t)e;
          rs[i] += e;
        }
      }
#pragma unroll
      for (int i = 0; i < 4; ++i) {  // reduce over the 16 col-lanes
        float s = rs[i];
        s += __shfl_xor(s, 1);
        s += __shfl_xor(s, 2);
        s += __shfl_xor(s, 4);
        s += __shfl_xor(s, 8);
        if (lr == 0) atomicAdd(&rowsum[row + i], s);
      }
    }
  } else {
    float* O = (float*)Cv;
#pragma unroll
    for (int mt = 0; mt < 8; ++mt) {
      const int row = m0 + (mt * 2 + wr) * 16 + hi4;
#pragma unroll
      for (int i = 0; i < 4; ++i) {
        const float inv = 1.0f / rowsum[row + i];
#pragma unroll
        for (int nt = 0; nt < 4; ++nt)
          O[(row + i) * N + n0 + (nt * 4 + wc) * 16 + lr] = acc[mt][nt][i] * inv;
      }
    }
  }
}

// ---------------------------------------------------------------- fallback (no ws)
__global__ __launch_bounds__(256) void hopfield_fallback(
    const float* __restrict__ x, const float* __restrict__ wl,
    const float* __restrict__ wc, float* __restrict__ out) {
  __shared__ float  xs[8 * 768];
  __shared__ bf16_t ps[8 * 4096];
  __shared__ float  rs[8];
  const int tid = threadIdx.x;
  const int r0  = blockIdx.x * 8;
  if (tid < 8) rs[tid] = 0.f;
  for (int i = tid; i < 8 * 768; i += 256)
    xs[i] = x[(r0 + (i / 768)) * 768 + (i % 768)];
  __syncthreads();

  float lsum[8] = {0, 0, 0, 0, 0, 0, 0, 0};
  for (int p = tid; p < 4096; p += 256) {
    float s[8] = {0, 0, 0, 0, 0, 0, 0, 0};
    for (int d = 0; d < 768; ++d) {
      const float wv = wl[p * 768 + d];
#pragma unroll
      for (int r = 0; r < 8; ++r) s[r] += xs[r * 768 + d] * wv;
    }
#pragma unroll
    for (int r = 0; r < 8; ++r) {
      const float e = __expf(s[r] * BETA_F);
      ps[r * 4096 + p] = (bf16_t)e;
      lsum[r] += e;
    }
  }
#pragma unroll
  for (int r = 0; r < 8; ++r) atomicAdd(&rs[r], lsum[r]);
  __syncthreads();

  for (int d = tid; d < 768; d += 256) {
    float o[8] = {0, 0, 0, 0, 0, 0, 0, 0};
    for (int p = 0; p < 4096; ++p) {
      const float wv = wc[d * 4096 + p];
#pragma unroll
      for (int r = 0; r < 8; ++r) o[r] += (float)ps[r * 4096 + p] * wv;
    }
#pragma unroll
    for (int r = 0; r < 8; ++r) out[(r0 + r) * 768 + d] = o[r] / rs[r];
  }
}

// ---------------------------------------------------------------- launcher
extern "C" void kernel_launch(void* const* d_in, const int* in_sizes, int n_in,
                              void* d_out, int out_size, void* d_ws, size_t ws_size,
                              hipStream_t stream) {
  (void)in_sizes; (void)n_in; (void)out_size;
  const float* x  = (const float*)d_in[0];
  const float* wl = (const float*)d_in[1];
  const float* wc = (const float*)d_in[2];
  float* out = (float*)d_out;

  const size_t xb_e = (size_t)NTOK * DIM;
  const size_t wl_e = (size_t)NPROT * DIM;
  const size_t wc_e = (size_t)DIM * NPROT;
  const size_t P_e  = (size_t)NTOK * NPROT;
  const size_t need = (xb_e + wl_e + wc_e + P_e) * 2 + (size_t)NTOK * 4;

  if (ws_size >= need) {
    char* ws = (char*)d_ws;
    bf16_t* xb  = (bf16_t*)ws;  ws += xb_e * 2;
    bf16_t* wlb = (bf16_t*)ws;  ws += wl_e * 2;
    bf16_t* wcb = (bf16_t*)ws;  ws += wc_e * 2;
    bf16_t* P   = (bf16_t*)ws;  ws += P_e * 2;
    float* rowsum = (float*)ws;

    hipMemsetAsync(rowsum, 0, NTOK * sizeof(float), stream);
    const int nx8 = (int)(xb_e / 8), nw8 = (int)(wl_e / 8), nc8 = (int)(wc_e / 8);
    cvt_all<<<(nx8 + nw8 + nc8 + 255) / 256, 256, 0, stream>>>(
        x, wl, wc, xb, wlb, wcb, nx8, nw8, nc8);
    // scores+exp+rowsum: M=16384, N=4096, K=768 -> 64x16 = 1024 blocks
    gemm256<0><<<dim3((NTOK / 256) * (NPROT / 256)), 512, 0, stream>>>(
        xb, wlb, (void*)P, rowsum, DIM, NPROT, NPROT / 256);
    // content+normalize: M=16384, N=768, K=4096 -> 64x3 = 192 blocks
    gemm256<1><<<dim3((NTOK / 256) * (DIM / 256)), 512, 0, stream>>>(
        P, wcb, (void*)out, rowsum, NPROT, DIM, DIM / 256);
  } else {
    hopfield_fallback<<<NTOK / 8, 256, 0, stream>>>(x, wl, wc, out);
  }
}

// Round 7
// 414.984 us; speedup vs baseline: 1.0993x; 1.0993x over previous
//
#include <hip/hip_runtime.h>
#include <hip/hip_bf16.h>

// HopfieldLayer: out = softmax(x @ Wl^T * beta) @ Wc^T
//   x [16384,768] f32, Wl [4096,768] f32, Wc [768,4096] f32 -> out [16384,768] f32
// R10: GEMM1 = R8 verbatim (best measured: fragment-ordered LDS, 8-phase,
// VM(6), bare barriers). GEMM2 rebuilt at BN=192 -> grid 64x4 = 256 blocks
// = 100% CU coverage (was 192/256 = 75% idle-proven). B staged as 3 thirds
// of 64 rows (1 load/thread, wave-uniform+lane*16), ledger VM(5)/K-tile:
// 12 outstanding -> drain 7 = next tile exactly. acc[8][3], LDS 112KB.

#define NTOK   16384
#define DIM    768
#define NPROT  4096
#define BETA_F 0.03608439182428583f

typedef __bf16 bf16_t;
typedef __bf16 bf16x8 __attribute__((ext_vector_type(8)));
typedef float  floatx4 __attribute__((ext_vector_type(4)));

// ---------------------------------------------------------------- async 16B copy
__device__ __forceinline__ void async_copy16(const bf16_t* g, void* l) {
  __builtin_amdgcn_global_load_lds(
      (__attribute__((address_space(1))) const void*)g,
      (__attribute__((address_space(3))) void*)l, 16, 0, 0);
}

// ---------------------------------------------------------------- f32 -> bf16
__global__ __launch_bounds__(256) void cvt_all(
    const float* __restrict__ x, const float* __restrict__ wl,
    const float* __restrict__ wc, bf16_t* __restrict__ xb,
    bf16_t* __restrict__ wlb, bf16_t* __restrict__ wcb,
    int nx8, int nw8, int nc8) {
  int i = blockIdx.x * 256 + threadIdx.x;
  const float* in; bf16_t* out; int k;
  if (i < nx8)            { in = x;  out = xb;  k = i; }
  else if (i < nx8 + nw8) { in = wl; out = wlb; k = i - nx8; }
  else if (i < nx8 + nw8 + nc8) { in = wc; out = wcb; k = i - nx8 - nw8; }
  else return;
  const float4* in4 = (const float4*)in;
  float4 a = in4[2 * k], b = in4[2 * k + 1];
  bf16x8 o;
  o[0] = (bf16_t)a.x; o[1] = (bf16_t)a.y; o[2] = (bf16_t)a.z; o[3] = (bf16_t)a.w;
  o[4] = (bf16_t)b.x; o[5] = (bf16_t)b.y; o[6] = (bf16_t)b.z; o[7] = (bf16_t)b.w;
  ((bf16x8*)out)[k] = o;
}

// ================================================================ GEMM1 (R8 verbatim)
// 256x256 tile, BK=64, 8 waves 2(M)x4(N), fragment-ordered LDS, 8-phase,
// VM(6) at P4/P8. EPI: P = exp(beta*acc) bf16 + rowsum atomics.
__global__ __launch_bounds__(512, 2)
void gemm256(const bf16_t* __restrict__ A, const bf16_t* __restrict__ B,
             bf16_t* __restrict__ P, float* __restrict__ rowsum,
             const int K, const int N, const int nN) {
  __shared__ char lds[131072];

  const int tid = threadIdx.x;
  const int l   = tid & 63;
  const int w   = tid >> 6;
  const int wr  = w >> 2;
  const int wc  = w & 3;
  const int lr  = l & 15;
  const int lk  = (l >> 4) << 3;

  const int nwg   = gridDim.x;
  const int chunk = nwg >> 3;
  const int wg    = (blockIdx.x & 7) * chunk + (blockIdx.x >> 3);
  const int m0    = (wg / nN) * 256;
  const int n0    = (wg % nN) * 256;

  int aoff[2][2], boff[2][2];
#pragma unroll
  for (int h = 0; h < 2; ++h)
#pragma unroll
    for (int j = 0; j < 2; ++j) {
      const int s     = j * 8 + w;
      const int mfrag = h * 8 + (s >> 1);
      const int ks    = s & 1;
      aoff[h][j] = (m0 + mfrag * 16 + lr) * K + ks * 32 + lk;
      boff[h][j] = (n0 + mfrag * 16 + lr) * K + ks * 32 + lk;
    }

  auto stageA = [&](int slot, int kt, int h) {
#pragma unroll
    for (int j = 0; j < 2; ++j) {
      const int s  = j * 8 + w;
      const int sf = (h * 8 + (s >> 1)) * 2 + (s & 1);
      async_copy16(A + aoff[h][j] + kt * 64, lds + slot * 65536 + sf * 1024);
    }
  };
  auto stageB = [&](int slot, int kt, int h) {
#pragma unroll
    for (int j = 0; j < 2; ++j) {
      const int s  = j * 8 + w;
      const int sf = (h * 8 + (s >> 1)) * 2 + (s & 1);
      async_copy16(B + boff[h][j] + kt * 64,
                   lds + slot * 65536 + 32768 + sf * 1024);
    }
  };

  bf16x8 af[4][2], bg[4][2];
  auto loadA = [&](int slot, int mh) {
#pragma unroll
    for (int q = 0; q < 4; ++q)
#pragma unroll
      for (int ks = 0; ks < 2; ++ks)
        af[q][ks] = *(const bf16x8*)(lds + slot * 65536 +
                        ((mh * 8 + q * 2 + wr) * 2 + ks) * 1024 + l * 16);
  };
  auto loadB = [&](int slot, int nh, int qb) {
#pragma unroll
    for (int q = 0; q < 2; ++q)
#pragma unroll
      for (int ks = 0; ks < 2; ++ks)
        bg[qb + q][ks] = *(const bf16x8*)(lds + slot * 65536 + 32768 +
                        ((nh * 8 + q * 4 + wc) * 2 + ks) * 1024 + l * 16);
  };

  const floatx4 z = {0.f, 0.f, 0.f, 0.f};
  floatx4 acc[8][4];
#pragma unroll
  for (int mt = 0; mt < 8; ++mt)
#pragma unroll
    for (int nt = 0; nt < 4; ++nt) acc[mt][nt] = z;

  auto mma = [&](int mq, int nq) {
    __builtin_amdgcn_s_setprio(1);
#pragma unroll
    for (int q = 0; q < 4; ++q)
#pragma unroll
      for (int r = 0; r < 2; ++r)
#pragma unroll
        for (int ks = 0; ks < 2; ++ks)
          acc[mq * 4 + q][nq * 2 + r] = __builtin_amdgcn_mfma_f32_16x16x32_bf16(
              af[q][ks], bg[nq * 2 + r][ks], acc[mq * 4 + q][nq * 2 + r], 0, 0, 0);
    __builtin_amdgcn_s_setprio(0);
  };

#define BAR()    __builtin_amdgcn_s_barrier()
#define LGKM0()  asm volatile("s_waitcnt lgkmcnt(0)")
#define LGKM8()  asm volatile("s_waitcnt lgkmcnt(8)")
#define VM(n)    asm volatile("s_waitcnt vmcnt(" #n ")" ::: "memory")

  const int T = K >> 6;

  stageA(0, 0, 0); stageB(0, 0, 0); stageB(0, 0, 1); stageA(0, 0, 1);
  stageA(1, 1, 0); stageB(1, 1, 0); stageB(1, 1, 1);
  VM(6);
  BAR();

#pragma unroll 1
  for (int t = 0; t < T - 2; t += 2) {
    loadA(0, 0); loadB(0, 0, 0);
    stageA(1, t + 1, 1);
    LGKM8();
    BAR(); LGKM0(); mma(0, 0); BAR();
    loadB(0, 1, 2);
    stageA(0, t + 2, 0);
    BAR(); LGKM0(); mma(0, 1); BAR();
    loadA(0, 1);
    stageB(0, t + 2, 0);
    BAR(); LGKM0(); mma(1, 1); BAR();
    stageB(0, t + 2, 1);
    BAR(); mma(1, 0); VM(6); BAR();
    loadA(1, 0); loadB(1, 0, 0);
    stageA(0, t + 2, 1);
    LGKM8();
    BAR(); LGKM0(); mma(0, 0); BAR();
    loadB(1, 1, 2);
    stageA(1, t + 3, 0);
    BAR(); LGKM0(); mma(0, 1); BAR();
    loadA(1, 1);
    stageB(1, t + 3, 0);
    BAR(); LGKM0(); mma(1, 1); BAR();
    stageB(1, t + 3, 1);
    BAR(); mma(1, 0); VM(6); BAR();
  }

  loadA(0, 0); loadB(0, 0, 0);
  stageA(1, T - 1, 1);
  LGKM8();
  BAR(); LGKM0(); mma(0, 0); BAR();
  loadB(0, 1, 2);
  BAR(); LGKM0(); mma(0, 1); BAR();
  loadA(0, 1);
  BAR(); LGKM0(); mma(1, 1); BAR();
  BAR(); mma(1, 0); VM(0); BAR();
  loadA(1, 0); loadB(1, 0, 0);
  BAR(); LGKM0(); mma(0, 0); BAR();
  loadB(1, 1, 2);
  BAR(); LGKM0(); mma(0, 1); BAR();
  loadA(1, 1);
  BAR(); LGKM0(); mma(1, 1); BAR();
  mma(1, 0);

  const int hi4 = (l >> 4) << 2;
#pragma unroll
  for (int mt = 0; mt < 8; ++mt) {
    const int row = m0 + (mt * 2 + wr) * 16 + hi4;
    float rs[4] = {0.f, 0.f, 0.f, 0.f};
#pragma unroll
    for (int nt = 0; nt < 4; ++nt) {
      const int col = n0 + (nt * 4 + wc) * 16 + lr;
#pragma unroll
      for (int i = 0; i < 4; ++i) {
        const float e = __expf(acc[mt][nt][i] * BETA_F);
        P[(row + i) * N + col] = (bf16_t)e;
        rs[i] += e;
      }
    }
#pragma unroll
    for (int i = 0; i < 4; ++i) {
      float s = rs[i];
      s += __shfl_xor(s, 1);
      s += __shfl_xor(s, 2);
      s += __shfl_xor(s, 4);
      s += __shfl_xor(s, 8);
      if (lr == 0) atomicAdd(&rowsum[row + i], s);
    }
  }
}

// ================================================================ GEMM2 (BN=192)
// C = A * B^T, A = P [16384 x 4096] bf16, B = wcb [768 x 4096] bf16.
// 256x192 tile, BK=64, grid 64x4 = 256 blocks (full CU coverage).
// 8 waves 2(M)x4(N): per-wave 128x48 = 8 mfrags x 3 nfrags. LDS/slot:
// A 32 subfrags (32KB) + B 24 subfrags (24KB) = 56KB; 2 slots = 112KB.
// B staged as 3 thirds of 64 rows: 1 load/thread, sf = t*8 + w.
// Ledger (7 loads/tile): P1 A(t+1)h1[2], P2 A(t+2)h0[2], P3 B(t+2)t01[2],
// P4 B(t+2)t2[1] + VM(5) (12 outstanding -> drain 7 = tile t+1 exactly).
__global__ __launch_bounds__(512, 2)
void gemm192(const bf16_t* __restrict__ A, const bf16_t* __restrict__ B,
             float* __restrict__ O, const float* __restrict__ rowsum,
             const int K, const int N) {
  __shared__ char lds[114688];   // 2 x 57344

  const int tid = threadIdx.x;
  const int l   = tid & 63;
  const int w   = tid >> 6;
  const int wr  = w >> 2;        // 0..1 (M)
  const int wc  = w & 3;         // 0..3 (N)
  const int lr  = l & 15;
  const int lk  = (l >> 4) << 3;

  // swizzle: nwg = 256, chunk = 32; nN = 4
  const int wg = (blockIdx.x & 7) * 32 + (blockIdx.x >> 3);
  const int m0 = (wg >> 2) * 256;
  const int n0 = (wg & 3) * 192;

  // A staging (identical scheme to gemm256): subfrag s=j*8+w per half
  int aoff[2][2];
#pragma unroll
  for (int h = 0; h < 2; ++h)
#pragma unroll
    for (int j = 0; j < 2; ++j) {
      const int s     = j * 8 + w;
      const int mfrag = h * 8 + (s >> 1);
      const int ks    = s & 1;
      aoff[h][j] = (m0 + mfrag * 16 + lr) * K + ks * 32 + lk;
    }
  // B staging: third t (64 rows), thread (w,l): frag = t*4 + (w>>1), ks = w&1
  int boff[3];
#pragma unroll
  for (int t = 0; t < 3; ++t)
    boff[t] = (n0 + (t * 4 + (w >> 1)) * 16 + lr) * K + (w & 1) * 32 + lk;

  auto stageA = [&](int slot, int kt, int h) {
#pragma unroll
    for (int j = 0; j < 2; ++j) {
      const int s  = j * 8 + w;
      const int sf = (h * 8 + (s >> 1)) * 2 + (s & 1);
      async_copy16(A + aoff[h][j] + kt * 64, lds + slot * 57344 + sf * 1024);
    }
  };
  auto stageBt = [&](int slot, int kt, int t) {
    async_copy16(B + boff[t] + kt * 64,
                 lds + slot * 57344 + 32768 + (t * 8 + w) * 1024 + l * 16);
  };

  bf16x8 af[4][2], bg[3][2];
  auto loadA = [&](int slot, int mh) {
#pragma unroll
    for (int q = 0; q < 4; ++q)
#pragma unroll
      for (int ks = 0; ks < 2; ++ks)
        af[q][ks] = *(const bf16x8*)(lds + slot * 57344 +
                        ((mh * 8 + q * 2 + wr) * 2 + ks) * 1024 + l * 16);
  };
  auto loadBn = [&](int slot, int nlo, int ncnt) {
    for (int r = 0; r < ncnt; ++r)
#pragma unroll
      for (int ks = 0; ks < 2; ++ks)
        bg[nlo + r][ks] = *(const bf16x8*)(lds + slot * 57344 + 32768 +
                        (((wc * 3 + nlo + r) * 2 + ks) << 10) + l * 16);
  };

  const floatx4 z = {0.f, 0.f, 0.f, 0.f};
  floatx4 acc[8][3];
#pragma unroll
  for (int mt = 0; mt < 8; ++mt)
#pragma unroll
    for (int nt = 0; nt < 3; ++nt) acc[mt][nt] = z;

  auto mma = [&](int mq, int nlo, int ncnt) {
    __builtin_amdgcn_s_setprio(1);
#pragma unroll
    for (int q = 0; q < 4; ++q)
      for (int r = 0; r < ncnt; ++r)
#pragma unroll
        for (int ks = 0; ks < 2; ++ks)
          acc[mq * 4 + q][nlo + r] = __builtin_amdgcn_mfma_f32_16x16x32_bf16(
              af[q][ks], bg[nlo + r][ks], acc[mq * 4 + q][nlo + r], 0, 0, 0);
    __builtin_amdgcn_s_setprio(0);
  };

  const int T = K >> 6;   // 64

  // prologue: tile0 full (7 loads) + tile1 {A h0, B t0..2} (5); A1h1 at P1
  stageA(0, 0, 0); stageA(0, 0, 1);
  stageBt(0, 0, 0); stageBt(0, 0, 1); stageBt(0, 0, 2);
  stageA(1, 1, 0);
  stageBt(1, 1, 0); stageBt(1, 1, 1); stageBt(1, 1, 2);
  VM(5);   // 12 outstanding -> drain 7 = tile0
  BAR();

#pragma unroll 1
  for (int t = 0; t < T - 2; t += 2) {
#pragma unroll
    for (int u = 0; u < 2; ++u) {      // tile t+u in slot u
      const int p = u;
      // P1: mLo x nt{0,1}; stage A(t+u+1)h1 -> slot p^1
      loadA(p, 0); loadBn(p, 0, 2);
      stageA(p ^ 1, t + u + 1, 1);
      LGKM8();
      BAR(); LGKM0(); mma(0, 0, 2); BAR();
      // P2: mLo x nt{2}; stage A(t+u+2)h0 -> slot p
      loadBn(p, 2, 1);
      stageA(p, t + u + 2, 0);
      BAR(); LGKM0(); mma(0, 2, 1); BAR();
      // P3: mHi x nt{0,1}; stage B(t+u+2) t0,t1 -> slot p
      loadA(p, 1);
      stageBt(p, t + u + 2, 0); stageBt(p, t + u + 2, 1);
      BAR(); LGKM0(); mma(1, 0, 2); BAR();
      // P4: mHi x nt{2}; stage B(t+u+2) t2; VM(5) -> tile t+u+1 landed
      stageBt(p, t + u + 2, 2);
      BAR(); mma(1, 2, 1); VM(5); BAR();
    }
  }

  // tail: tiles T-2 (slot0), T-1 (slot1); only A(T-1)h1 left to stage
  loadA(0, 0); loadBn(0, 0, 2);
  stageA(1, T - 1, 1);
  LGKM8();
  BAR(); LGKM0(); mma(0, 0, 2); BAR();
  loadBn(0, 2, 1);
  BAR(); LGKM0(); mma(0, 2, 1); BAR();
  loadA(0, 1);
  BAR(); LGKM0(); mma(1, 0, 2); BAR();
  BAR(); mma(1, 2, 1); VM(0); BAR();
  loadA(1, 0); loadBn(1, 0, 2);
  BAR(); LGKM0(); mma(0, 0, 2); BAR();
  loadBn(1, 2, 1);
  BAR(); LGKM0(); mma(0, 2, 1); BAR();
  loadA(1, 1);
  BAR(); LGKM0(); mma(1, 0, 2); BAR();
  mma(1, 2, 1);

#undef BAR
#undef LGKM0
#undef LGKM8
#undef VM

  // epilogue: O = acc / rowsum[row]
  const int hi4 = (l >> 4) << 2;
#pragma unroll
  for (int mt = 0; mt < 8; ++mt) {
    const int row = m0 + (mt * 2 + wr) * 16 + hi4;
#pragma unroll
    for (int i = 0; i < 4; ++i) {
      const float inv = 1.0f / rowsum[row + i];
#pragma unroll
      for (int nt = 0; nt < 3; ++nt)
        O[(row + i) * N + n0 + (wc * 3 + nt) * 16 + lr] = acc[mt][nt][i] * inv;
    }
  }
}

// ---------------------------------------------------------------- fallback (no ws)
__global__ __launch_bounds__(256) void hopfield_fallback(
    const float* __restrict__ x, const float* __restrict__ wl,
    const float* __restrict__ wc, float* __restrict__ out) {
  __shared__ float  xs[8 * 768];
  __shared__ bf16_t ps[8 * 4096];
  __shared__ float  rs[8];
  const int tid = threadIdx.x;
  const int r0  = blockIdx.x * 8;
  if (tid < 8) rs[tid] = 0.f;
  for (int i = tid; i < 8 * 768; i += 256)
    xs[i] = x[(r0 + (i / 768)) * 768 + (i % 768)];
  __syncthreads();

  float lsum[8] = {0, 0, 0, 0, 0, 0, 0, 0};
  for (int p = tid; p < 4096; p += 256) {
    float s[8] = {0, 0, 0, 0, 0, 0, 0, 0};
    for (int d = 0; d < 768; ++d) {
      const float wv = wl[p * 768 + d];
#pragma unroll
      for (int r = 0; r < 8; ++r) s[r] += xs[r * 768 + d] * wv;
    }
#pragma unroll
    for (int r = 0; r < 8; ++r) {
      const float e = __expf(s[r] * BETA_F);
      ps[r * 4096 + p] = (bf16_t)e;
      lsum[r] += e;
    }
  }
#pragma unroll
  for (int r = 0; r < 8; ++r) atomicAdd(&rs[r], lsum[r]);
  __syncthreads();

  for (int d = tid; d < 768; d += 256) {
    float o[8] = {0, 0, 0, 0, 0, 0, 0, 0};
    for (int p = 0; p < 4096; ++p) {
      const float wv = wc[d * 4096 + p];
#pragma unroll
      for (int r = 0; r < 8; ++r) o[r] += (float)ps[r * 4096 + p] * wv;
    }
#pragma unroll
    for (int r = 0; r < 8; ++r) out[(r0 + r) * 768 + d] = o[r] / rs[r];
  }
}

// ---------------------------------------------------------------- launcher
extern "C" void kernel_launch(void* const* d_in, const int* in_sizes, int n_in,
                              void* d_out, int out_size, void* d_ws, size_t ws_size,
                              hipStream_t stream) {
  (void)in_sizes; (void)n_in; (void)out_size;
  const float* x  = (const float*)d_in[0];
  const float* wl = (const float*)d_in[1];
  const float* wc = (const float*)d_in[2];
  float* out = (float*)d_out;

  const size_t xb_e = (size_t)NTOK * DIM;
  const size_t wl_e = (size_t)NPROT * DIM;
  const size_t wc_e = (size_t)DIM * NPROT;
  const size_t P_e  = (size_t)NTOK * NPROT;
  const size_t need = (xb_e + wl_e + wc_e + P_e) * 2 + (size_t)NTOK * 4;

  if (ws_size >= need) {
    char* ws = (char*)d_ws;
    bf16_t* xb  = (bf16_t*)ws;  ws += xb_e * 2;
    bf16_t* wlb = (bf16_t*)ws;  ws += wl_e * 2;
    bf16_t* wcb = (bf16_t*)ws;  ws += wc_e * 2;
    bf16_t* P   = (bf16_t*)ws;  ws += P_e * 2;
    float* rowsum = (float*)ws;

    hipMemsetAsync(rowsum, 0, NTOK * sizeof(float), stream);
    const int nx8 = (int)(xb_e / 8), nw8 = (int)(wl_e / 8), nc8 = (int)(wc_e / 8);
    cvt_all<<<(nx8 + nw8 + nc8 + 255) / 256, 256, 0, stream>>>(
        x, wl, wc, xb, wlb, wcb, nx8, nw8, nc8);
    // scores+exp+rowsum: M=16384, N=4096, K=768 -> 64x16 = 1024 blocks
    gemm256<<<dim3((NTOK / 256) * (NPROT / 256)), 512, 0, stream>>>(
        xb, wlb, P, rowsum, DIM, NPROT, NPROT / 256);
    // content+normalize: M=16384, N=768, K=4096 -> 64x4 = 256 blocks (BN=192)
    gemm192<<<dim3(256), 512, 0, stream>>>(
        P, wcb, out, rowsum, NPROT, DIM);
  } else {
    hopfield_fallback<<<NTOK / 8, 256, 0, stream>>>(x, wl, wc, out);
  }
}

// Round 8
// 385.817 us; speedup vs baseline: 1.1824x; 1.0756x over previous
//
#include <hip/hip_runtime.h>
#include <hip/hip_bf16.h>

// HopfieldLayer: out = softmax(x @ Wl^T * beta) @ Wc^T
//   x [16384,768] f32, Wl [4096,768] f32, Wc [768,4096] f32 -> out [16384,768] f32
// R11: clean test of the staging SOURCE pattern. xb/wlb/wcb are pre-packed by
// cvt_all into fragment-tile-major order: packed[(band*T+kt)*NSF + sf][l][8]
// so EVERY global_load_lds reads 1KB fully contiguous (4 lines) instead of
// 16 scattered 64B segments. GEMM kernels byte-identical to R10 except the
// stage source address; LDS dest/reads/ledger/schedule untouched (verified).
// GEMM2's A (=P) stays row-major/scattered -- within-round control.

#define NTOK   16384
#define DIM    768
#define NPROT  4096
#define BETA_F 0.03608439182428583f

typedef __bf16 bf16_t;
typedef __bf16 bf16x8 __attribute__((ext_vector_type(8)));
typedef float  floatx4 __attribute__((ext_vector_type(4)));

// ---------------------------------------------------------------- async 16B copy
__device__ __forceinline__ void async_copy16(const bf16_t* g, void* l) {
  __builtin_amdgcn_global_load_lds(
      (__attribute__((address_space(1))) const void*)g,
      (__attribute__((address_space(3))) void*)l, 16, 0, 0);
}

// ---------------------------------------------------------------- f32 -> bf16 + pack
// pack element (band,kt,sf,l,e) = src[band*256 + (sf>>1)*16 + (l&15)]
//                                    [kt*64 + (sf&1)*32 + (l>>4)*8 + e]
// x:  16384x768 -> 64 bands x T=12 x 32 sf     wl: 4096x768 -> 16 x 12 x 32
// wc: 768x4096, 192-row bands -> 4 nb x T=64 x 24 sf (sf = frag*2+ks, frag<12)
__global__ __launch_bounds__(256) void cvt_all(
    const float* __restrict__ x, const float* __restrict__ wl,
    const float* __restrict__ wc, bf16_t* __restrict__ xb,
    bf16_t* __restrict__ wlb, bf16_t* __restrict__ wcb,
    int nx8, int nw8, int nc8) {
  int i = blockIdx.x * 256 + threadIdx.x;
  const float* in; bf16_t* out; int k; int dv;
  if (i < nx8) {
    in = x; out = xb; k = i;
    const int m = k / 96, kv = k % 96;          // 96 vec8 per row (K=768)
    const int kt = kv >> 3, kr = kv & 7;
    const int sf = (((m >> 4) & 15) << 1) + (kr >> 2);
    const int l  = (m & 15) + ((kr & 3) << 4);
    dv = (((m >> 8) * 12 + kt) * 32 + sf) * 64 + l;
  } else if (i < nx8 + nw8) {
    in = wl; out = wlb; k = i - nx8;
    const int p = k / 96, kv = k % 96;
    const int kt = kv >> 3, kr = kv & 7;
    const int sf = (((p >> 4) & 15) << 1) + (kr >> 2);
    const int l  = (p & 15) + ((kr & 3) << 4);
    dv = (((p >> 8) * 12 + kt) * 32 + sf) * 64 + l;
  } else if (i < nx8 + nw8 + nc8) {
    in = wc; out = wcb; k = i - nx8 - nw8;
    const int d = k / 512, pv = k % 512;        // 512 vec8 per row (K=4096)
    const int kt = pv >> 3, kr = pv & 7;
    const int dd = d % 192;
    const int sf = ((dd >> 4) << 1) + (kr >> 2);
    const int l  = (dd & 15) + ((kr & 3) << 4);
    dv = (((d / 192) * 64 + kt) * 24 + sf) * 64 + l;
  } else return;
  const float4* in4 = (const float4*)in;
  float4 a = in4[2 * k], b = in4[2 * k + 1];
  bf16x8 o;
  o[0] = (bf16_t)a.x; o[1] = (bf16_t)a.y; o[2] = (bf16_t)a.z; o[3] = (bf16_t)a.w;
  o[4] = (bf16_t)b.x; o[5] = (bf16_t)b.y; o[6] = (bf16_t)b.z; o[7] = (bf16_t)b.w;
  ((bf16x8*)out)[dv] = o;
}

// ================================================================ GEMM1 (R8 core)
// A,B packed: stage source = ((band*T+kt)*32+sf)*512 + l*8 -- 1KB contiguous
// per instruction. Everything else identical to R10's gemm256.
__global__ __launch_bounds__(512, 2)
void gemm256(const bf16_t* __restrict__ A, const bf16_t* __restrict__ B,
             bf16_t* __restrict__ P, float* __restrict__ rowsum,
             const int K, const int N, const int nN) {
  __shared__ char lds[131072];

  const int tid = threadIdx.x;
  const int l   = tid & 63;
  const int w   = tid >> 6;
  const int wr  = w >> 2;
  const int wc  = w & 3;
  const int lr  = l & 15;

  const int nwg   = gridDim.x;
  const int chunk = nwg >> 3;
  const int wg    = (blockIdx.x & 7) * chunk + (blockIdx.x >> 3);
  const int m0    = (wg / nN) * 256;
  const int n0    = (wg % nN) * 256;

  const int T = K >> 6;
  // packed staging bases: sf = (h*8+(s>>1))*2 + (s&1), s = j*8+w
  const int abase = (m0 >> 8) * T * 16384 + l * 8;   // + kt*16384 + sf*512
  const int bbase = (n0 >> 8) * T * 16384 + l * 8;
  int asf[2][2], bsf[2][2];
#pragma unroll
  for (int h = 0; h < 2; ++h)
#pragma unroll
    for (int j = 0; j < 2; ++j) {
      const int s = j * 8 + w;
      asf[h][j] = ((h * 8 + (s >> 1)) * 2 + (s & 1)) * 512;
      bsf[h][j] = asf[h][j];
    }

  auto stageA = [&](int slot, int kt, int h) {
#pragma unroll
    for (int j = 0; j < 2; ++j) {
      const int s  = j * 8 + w;
      const int sf = (h * 8 + (s >> 1)) * 2 + (s & 1);
      async_copy16(A + abase + kt * 16384 + asf[h][j],
                   lds + slot * 65536 + sf * 1024);
    }
  };
  auto stageB = [&](int slot, int kt, int h) {
#pragma unroll
    for (int j = 0; j < 2; ++j) {
      const int s  = j * 8 + w;
      const int sf = (h * 8 + (s >> 1)) * 2 + (s & 1);
      async_copy16(B + bbase + kt * 16384 + bsf[h][j],
                   lds + slot * 65536 + 32768 + sf * 1024);
    }
  };

  bf16x8 af[4][2], bg[4][2];
  auto loadA = [&](int slot, int mh) {
#pragma unroll
    for (int q = 0; q < 4; ++q)
#pragma unroll
      for (int ks = 0; ks < 2; ++ks)
        af[q][ks] = *(const bf16x8*)(lds + slot * 65536 +
                        ((mh * 8 + q * 2 + wr) * 2 + ks) * 1024 + l * 16);
  };
  auto loadB = [&](int slot, int nh, int qb) {
#pragma unroll
    for (int q = 0; q < 2; ++q)
#pragma unroll
      for (int ks = 0; ks < 2; ++ks)
        bg[qb + q][ks] = *(const bf16x8*)(lds + slot * 65536 + 32768 +
                        ((nh * 8 + q * 4 + wc) * 2 + ks) * 1024 + l * 16);
  };

  const floatx4 z = {0.f, 0.f, 0.f, 0.f};
  floatx4 acc[8][4];
#pragma unroll
  for (int mt = 0; mt < 8; ++mt)
#pragma unroll
    for (int nt = 0; nt < 4; ++nt) acc[mt][nt] = z;

  auto mma = [&](int mq, int nq) {
    __builtin_amdgcn_s_setprio(1);
#pragma unroll
    for (int q = 0; q < 4; ++q)
#pragma unroll
      for (int r = 0; r < 2; ++r)
#pragma unroll
        for (int ks = 0; ks < 2; ++ks)
          acc[mq * 4 + q][nq * 2 + r] = __builtin_amdgcn_mfma_f32_16x16x32_bf16(
              af[q][ks], bg[nq * 2 + r][ks], acc[mq * 4 + q][nq * 2 + r], 0, 0, 0);
    __builtin_amdgcn_s_setprio(0);
  };

#define BAR()    __builtin_amdgcn_s_barrier()
#define LGKM0()  asm volatile("s_waitcnt lgkmcnt(0)")
#define LGKM8()  asm volatile("s_waitcnt lgkmcnt(8)")
#define VM(n)    asm volatile("s_waitcnt vmcnt(" #n ")" ::: "memory")

  stageA(0, 0, 0); stageB(0, 0, 0); stageB(0, 0, 1); stageA(0, 0, 1);
  stageA(1, 1, 0); stageB(1, 1, 0); stageB(1, 1, 1);
  VM(6);
  BAR();

#pragma unroll 1
  for (int t = 0; t < T - 2; t += 2) {
    loadA(0, 0); loadB(0, 0, 0);
    stageA(1, t + 1, 1);
    LGKM8();
    BAR(); LGKM0(); mma(0, 0); BAR();
    loadB(0, 1, 2);
    stageA(0, t + 2, 0);
    BAR(); LGKM0(); mma(0, 1); BAR();
    loadA(0, 1);
    stageB(0, t + 2, 0);
    BAR(); LGKM0(); mma(1, 1); BAR();
    stageB(0, t + 2, 1);
    BAR(); mma(1, 0); VM(6); BAR();
    loadA(1, 0); loadB(1, 0, 0);
    stageA(0, t + 2, 1);
    LGKM8();
    BAR(); LGKM0(); mma(0, 0); BAR();
    loadB(1, 1, 2);
    stageA(1, t + 3, 0);
    BAR(); LGKM0(); mma(0, 1); BAR();
    loadA(1, 1);
    stageB(1, t + 3, 0);
    BAR(); LGKM0(); mma(1, 1); BAR();
    stageB(1, t + 3, 1);
    BAR(); mma(1, 0); VM(6); BAR();
  }

  loadA(0, 0); loadB(0, 0, 0);
  stageA(1, T - 1, 1);
  LGKM8();
  BAR(); LGKM0(); mma(0, 0); BAR();
  loadB(0, 1, 2);
  BAR(); LGKM0(); mma(0, 1); BAR();
  loadA(0, 1);
  BAR(); LGKM0(); mma(1, 1); BAR();
  BAR(); mma(1, 0); VM(0); BAR();
  loadA(1, 0); loadB(1, 0, 0);
  BAR(); LGKM0(); mma(0, 0); BAR();
  loadB(1, 1, 2);
  BAR(); LGKM0(); mma(0, 1); BAR();
  loadA(1, 1);
  BAR(); LGKM0(); mma(1, 1); BAR();
  mma(1, 0);

  const int hi4 = (l >> 4) << 2;
#pragma unroll
  for (int mt = 0; mt < 8; ++mt) {
    const int row = m0 + (mt * 2 + wr) * 16 + hi4;
    float rs[4] = {0.f, 0.f, 0.f, 0.f};
#pragma unroll
    for (int nt = 0; nt < 4; ++nt) {
      const int col = n0 + (nt * 4 + wc) * 16 + lr;
#pragma unroll
      for (int i = 0; i < 4; ++i) {
        const float e = __expf(acc[mt][nt][i] * BETA_F);
        P[(row + i) * N + col] = (bf16_t)e;
        rs[i] += e;
      }
    }
#pragma unroll
    for (int i = 0; i < 4; ++i) {
      float s = rs[i];
      s += __shfl_xor(s, 1);
      s += __shfl_xor(s, 2);
      s += __shfl_xor(s, 4);
      s += __shfl_xor(s, 8);
      if (lr == 0) atomicAdd(&rowsum[row + i], s);
    }
  }
}

// ================================================================ GEMM2 (BN=192)
// A = P row-major (unpacked -- control); B = wcb packed (1KB bursts).
__global__ __launch_bounds__(512, 2)
void gemm192(const bf16_t* __restrict__ A, const bf16_t* __restrict__ B,
             float* __restrict__ O, const float* __restrict__ rowsum,
             const int K, const int N) {
  __shared__ char lds[114688];   // 2 x 57344

  const int tid = threadIdx.x;
  const int l   = tid & 63;
  const int w   = tid >> 6;
  const int wr  = w >> 2;
  const int wc  = w & 3;
  const int lr  = l & 15;
  const int lk  = (l >> 4) << 3;

  const int wg = (blockIdx.x & 7) * 32 + (blockIdx.x >> 3);
  const int m0 = (wg >> 2) * 256;
  const int n0 = (wg & 3) * 192;

  // A (row-major, scattered -- control)
  int aoff[2][2];
#pragma unroll
  for (int h = 0; h < 2; ++h)
#pragma unroll
    for (int j = 0; j < 2; ++j) {
      const int s     = j * 8 + w;
      const int mfrag = h * 8 + (s >> 1);
      const int ks    = s & 1;
      aoff[h][j] = (m0 + mfrag * 16 + lr) * K + ks * 32 + lk;
    }
  // B packed: nb = n0/192, T=64, 24 sf; sfb = t*8 + w
  const int bb = (n0 / 192) * 64 * 12288 + l * 8;   // + kt*12288 + sfb*512
  int bsf[3];
#pragma unroll
  for (int t = 0; t < 3; ++t) bsf[t] = (t * 8 + w) * 512;

  auto stageA = [&](int slot, int kt, int h) {
#pragma unroll
    for (int j = 0; j < 2; ++j) {
      const int s  = j * 8 + w;
      const int sf = (h * 8 + (s >> 1)) * 2 + (s & 1);
      async_copy16(A + aoff[h][j] + kt * 64, lds + slot * 57344 + sf * 1024);
    }
  };
  auto stageBt = [&](int slot, int kt, int t) {
    async_copy16(B + bb + kt * 12288 + bsf[t],
                 lds + slot * 57344 + 32768 + (t * 8 + w) * 1024 + l * 16);
  };

  bf16x8 af[4][2], bg[3][2];
  auto loadA = [&](int slot, int mh) {
#pragma unroll
    for (int q = 0; q < 4; ++q)
#pragma unroll
      for (int ks = 0; ks < 2; ++ks)
        af[q][ks] = *(const bf16x8*)(lds + slot * 57344 +
                        ((mh * 8 + q * 2 + wr) * 2 + ks) * 1024 + l * 16);
  };
  auto loadBn = [&](int slot, int nlo, int ncnt) {
    for (int r = 0; r < ncnt; ++r)
#pragma unroll
      for (int ks = 0; ks < 2; ++ks)
        bg[nlo + r][ks] = *(const bf16x8*)(lds + slot * 57344 + 32768 +
                        (((wc * 3 + nlo + r) * 2 + ks) << 10) + l * 16);
  };

  const floatx4 z = {0.f, 0.f, 0.f, 0.f};
  floatx4 acc[8][3];
#pragma unroll
  for (int mt = 0; mt < 8; ++mt)
#pragma unroll
    for (int nt = 0; nt < 3; ++nt) acc[mt][nt] = z;

  auto mma = [&](int mq, int nlo, int ncnt) {
    __builtin_amdgcn_s_setprio(1);
#pragma unroll
    for (int q = 0; q < 4; ++q)
      for (int r = 0; r < ncnt; ++r)
#pragma unroll
        for (int ks = 0; ks < 2; ++ks)
          acc[mq * 4 + q][nlo + r] = __builtin_amdgcn_mfma_f32_16x16x32_bf16(
              af[q][ks], bg[nlo + r][ks], acc[mq * 4 + q][nlo + r], 0, 0, 0);
    __builtin_amdgcn_s_setprio(0);
  };

  const int T = K >> 6;   // 64

  stageA(0, 0, 0); stageA(0, 0, 1);
  stageBt(0, 0, 0); stageBt(0, 0, 1); stageBt(0, 0, 2);
  stageA(1, 1, 0);
  stageBt(1, 1, 0); stageBt(1, 1, 1); stageBt(1, 1, 2);
  VM(5);
  BAR();

#pragma unroll 1
  for (int t = 0; t < T - 2; t += 2) {
#pragma unroll
    for (int u = 0; u < 2; ++u) {
      const int p = u;
      loadA(p, 0); loadBn(p, 0, 2);
      stageA(p ^ 1, t + u + 1, 1);
      LGKM8();
      BAR(); LGKM0(); mma(0, 0, 2); BAR();
      loadBn(p, 2, 1);
      stageA(p, t + u + 2, 0);
      BAR(); LGKM0(); mma(0, 2, 1); BAR();
      loadA(p, 1);
      stageBt(p, t + u + 2, 0); stageBt(p, t + u + 2, 1);
      BAR(); LGKM0(); mma(1, 0, 2); BAR();
      stageBt(p, t + u + 2, 2);
      BAR(); mma(1, 2, 1); VM(5); BAR();
    }
  }

  loadA(0, 0); loadBn(0, 0, 2);
  stageA(1, T - 1, 1);
  LGKM8();
  BAR(); LGKM0(); mma(0, 0, 2); BAR();
  loadBn(0, 2, 1);
  BAR(); LGKM0(); mma(0, 2, 1); BAR();
  loadA(0, 1);
  BAR(); LGKM0(); mma(1, 0, 2); BAR();
  BAR(); mma(1, 2, 1); VM(0); BAR();
  loadA(1, 0); loadBn(1, 0, 2);
  BAR(); LGKM0(); mma(0, 0, 2); BAR();
  loadBn(1, 2, 1);
  BAR(); LGKM0(); mma(0, 2, 1); BAR();
  loadA(1, 1);
  BAR(); LGKM0(); mma(1, 0, 2); BAR();
  mma(1, 2, 1);

#undef BAR
#undef LGKM0
#undef LGKM8
#undef VM

  const int hi4 = (l >> 4) << 2;
#pragma unroll
  for (int mt = 0; mt < 8; ++mt) {
    const int row = m0 + (mt * 2 + wr) * 16 + hi4;
#pragma unroll
    for (int i = 0; i < 4; ++i) {
      const float inv = 1.0f / rowsum[row + i];
#pragma unroll
      for (int nt = 0; nt < 3; ++nt)
        O[(row + i) * N + n0 + (wc * 3 + nt) * 16 + lr] = acc[mt][nt][i] * inv;
    }
  }
}

// ---------------------------------------------------------------- fallback (no ws)
__global__ __launch_bounds__(256) void hopfield_fallback(
    const float* __restrict__ x, const float* __restrict__ wl,
    const float* __restrict__ wc, float* __restrict__ out) {
  __shared__ float  xs[8 * 768];
  __shared__ bf16_t ps[8 * 4096];
  __shared__ float  rs[8];
  const int tid = threadIdx.x;
  const int r0  = blockIdx.x * 8;
  if (tid < 8) rs[tid] = 0.f;
  for (int i = tid; i < 8 * 768; i += 256)
    xs[i] = x[(r0 + (i / 768)) * 768 + (i % 768)];
  __syncthreads();

  float lsum[8] = {0, 0, 0, 0, 0, 0, 0, 0};
  for (int p = tid; p < 4096; p += 256) {
    float s[8] = {0, 0, 0, 0, 0, 0, 0, 0};
    for (int d = 0; d < 768; ++d) {
      const float wv = wl[p * 768 + d];
#pragma unroll
      for (int r = 0; r < 8; ++r) s[r] += xs[r * 768 + d] * wv;
    }
#pragma unroll
    for (int r = 0; r < 8; ++r) {
      const float e = __expf(s[r] * BETA_F);
      ps[r * 4096 + p] = (bf16_t)e;
      lsum[r] += e;
    }
  }
#pragma unroll
  for (int r = 0; r < 8; ++r) atomicAdd(&rs[r], lsum[r]);
  __syncthreads();

  for (int d = tid; d < 768; d += 256) {
    float o[8] = {0, 0, 0, 0, 0, 0, 0, 0};
    for (int p = 0; p < 4096; ++p) {
      const float wv = wc[d * 4096 + p];
#pragma unroll
      for (int r = 0; r < 8; ++r) o[r] += (float)ps[r * 4096 + p] * wv;
    }
#pragma unroll
    for (int r = 0; r < 8; ++r) out[(r0 + r) * 768 + d] = o[r] / rs[r];
  }
}

// ---------------------------------------------------------------- launcher
extern "C" void kernel_launch(void* const* d_in, const int* in_sizes, int n_in,
                              void* d_out, int out_size, void* d_ws, size_t ws_size,
                              hipStream_t stream) {
  (void)in_sizes; (void)n_in; (void)out_size;
  const float* x  = (const float*)d_in[0];
  const float* wl = (const float*)d_in[1];
  const float* wc = (const float*)d_in[2];
  float* out = (float*)d_out;

  const size_t xb_e = (size_t)NTOK * DIM;
  const size_t wl_e = (size_t)NPROT * DIM;
  const size_t wc_e = (size_t)DIM * NPROT;
  const size_t P_e  = (size_t)NTOK * NPROT;
  const size_t need = (xb_e + wl_e + wc_e + P_e) * 2 + (size_t)NTOK * 4;

  if (ws_size >= need) {
    char* ws = (char*)d_ws;
    bf16_t* xb  = (bf16_t*)ws;  ws += xb_e * 2;
    bf16_t* wlb = (bf16_t*)ws;  ws += wl_e * 2;
    bf16_t* wcb = (bf16_t*)ws;  ws += wc_e * 2;
    bf16_t* P   = (bf16_t*)ws;  ws += P_e * 2;
    float* rowsum = (float*)ws;

    hipMemsetAsync(rowsum, 0, NTOK * sizeof(float), stream);
    const int nx8 = (int)(xb_e / 8), nw8 = (int)(wl_e / 8), nc8 = (int)(wc_e / 8);
    cvt_all<<<(nx8 + nw8 + nc8 + 255) / 256, 256, 0, stream>>>(
        x, wl, wc, xb, wlb, wcb, nx8, nw8, nc8);
    // scores+exp+rowsum: M=16384, N=4096, K=768 -> 64x16 = 1024 blocks
    gemm256<<<dim3((NTOK / 256) * (NPROT / 256)), 512, 0, stream>>>(
        xb, wlb, P, rowsum, DIM, NPROT, NPROT / 256);
    // content+normalize: M=16384, N=768, K=4096 -> 64x4 = 256 blocks (BN=192)
    gemm192<<<dim3(256), 512, 0, stream>>>(
        P, wcb, out, rowsum, NPROT, DIM);
  } else {
    hopfield_fallback<<<NTOK / 8, 256, 0, stream>>>(x, wl, wc, out);
  }
}